// Round 9
// baseline (145.320 us; speedup 1.0000x reference)
//
#include <hip/hip_runtime.h>

#define SEQ 8192
#define DIM 128
#define QR  4                          // query rows per wave
#define WPB 8                          // waves per block (512 threads)
#define RPB (QR * WPB)                 // 32 rows per block
#define NB  (2 * SEQ / RPB)            // 512 blocks
#define SROWS 96                       // staged K/V rows: [blkrow0-64, blkrow0+31]

// R9 = MEASUREMENT ROUND. Kernel is R8 verbatim; kernel_launch runs it 4x
// back-to-back (idempotent) so the benched total exposes the per-pass kernel
// time: dur_us = overhead + Tk_cold + 3*Tk_warm. Decision table in journal.
//
// fp32 in / fp32 out. One wave handles QR=4 consecutive query rows [r0,r0+3];
// lane l owns key j = r0-60+l. Row rr's window is [r0-60, r0+rr] (61..64
// keys); dropped keys carry bias <= -61 -> relative weight < e^-50, invisible
// at fp32. Global sinks (j<100) only matter inside this window (rows i<164).
__global__ __launch_bounds__(512) void lminf_kernel(
    const float* __restrict__ qg,
    const float* __restrict__ kg,
    const float* __restrict__ vg,
    float* __restrict__ og)
{
    const int tid  = threadIdx.x;
    const int lane = tid & 63;
    const int wv   = __builtin_amdgcn_readfirstlane(tid >> 6);  // uniform 0..7

    const int wk      = ((blockIdx.x & 7) << 6) + (blockIdx.x >> 3);
    const int rowblk  = wk * RPB + wv * QR;          // wave's first query row
    const int r0      = rowblk & (SEQ - 1);
    const int blkrow0 = (wk * RPB) & (SEQ - 1);      // block's first row
    const long base   = (long)((wk * RPB) >> 13) * (SEQ * DIM);

    __shared__ float4 kds[SROWS * 32];               // 48 KB, chunk c at c^(row&7)
    __shared__ float4 vds[SROWS * 32];               // 48 KB, linear
    __shared__ float4 wsm[WPB][64];                  // 8 KB, per-key packed e

    // ---- burst-stage K (XOR-swizzled) and V (linear), fully coalesced ----
    {
        const float4* kgp = (const float4*)(kg + base);
        const float4* vgp = (const float4*)(vg + base);
        #pragma unroll
        for (int it = 0; it < (SROWS * 32) / 512; ++it) {   // 6 iters
            const int g   = it * 512 + tid;
            const int row = g >> 5;
            const int c   = g & 31;
            int gr = blkrow0 - 64 + row;
            if (gr < 0) gr = 0;                 // clamped rows get weight 0
            kds[row * 32 + (c ^ (row & 7))] = kgp[gr * 32 + c];
            vds[row * 32 + c]               = vgp[gr * 32 + c];
        }
    }
    __syncthreads();

    // ---- QK: K via swizzled ds_read_b128; q via wave-uniform s_load ----
    const int w0 = r0 - 60;                     // key owned by lane 0
    const int j  = w0 + lane;
    const int lr = lane + wv * QR + 4;          // staged local row of key j
    const int sw = lr & 7;
    const float4* krow = &kds[lr * 32];
    const float* qb = qg + base + (long)r0 * DIM;   // wave-uniform

    float acc[QR] = {0.f, 0.f, 0.f, 0.f};
    #pragma unroll 8
    for (int c = 0; c < 32; ++c) {
        const float4 kk = krow[c ^ sw];
        #pragma unroll
        for (int rr = 0; rr < QR; ++rr) {
            const float4 qq = *(const float4*)(qb + rr * DIM + c * 4);
            acc[rr] += qq.x * kk.x + qq.y * kk.y + qq.z * kk.z + qq.w * kk.w;
        }
    }

    // ---- shuffle-free softmax numerator: fixed stabilizer M = 8 ----
    float e[QR];
    #pragma unroll
    for (int rr = 0; rr < QR; ++rr) {
        const int i = r0 + rr;
        float s = acc[rr] * 0.08838834764831845f + (float)(j - i);  // bias
        if (j > i || j < 0) s = -3.0e38f;       // causal + left-edge mask
        e[rr] = __expf(s - 8.0f);               // masked lanes -> exact 0
    }
    wsm[wv][lane] = make_float4(e[0], e[1], e[2], e[3]);

    // ---- PV: pure LDS; weights uniform broadcast; l folded into loop ----
    float o0[QR] = {0.f, 0.f, 0.f, 0.f};
    float o1[QR] = {0.f, 0.f, 0.f, 0.f};
    float lsum[QR] = {0.f, 0.f, 0.f, 0.f};
    #pragma unroll 16
    for (int k = 0; k < 64; ++k) {
        const float2 vpair = *(const float2*)(
            (const float*)&vds[(k + wv * QR + 4) * 32] + 2 * lane);
        const float4 wk4 = wsm[wv][k];          // uniform addr -> broadcast
        lsum[0] += wk4.x;  lsum[1] += wk4.y;
        lsum[2] += wk4.z;  lsum[3] += wk4.w;
        o0[0] += wk4.x * vpair.x;  o1[0] += wk4.x * vpair.y;
        o0[1] += wk4.y * vpair.x;  o1[1] += wk4.y * vpair.y;
        o0[2] += wk4.z * vpair.x;  o1[2] += wk4.z * vpair.y;
        o0[3] += wk4.w * vpair.x;  o1[3] += wk4.w * vpair.y;
    }

    // ---- normalize and store (coalesced float2 per lane per row) ----
    #pragma unroll
    for (int rr = 0; rr < QR; ++rr) {
        const float rl = 1.0f / lsum[rr];       // l >= e^-14 > 0 always
        ((float2*)(og + base + (long)(r0 + rr) * DIM))[lane] =
            make_float2(o0[rr] * rl, o1[rr] * rl);
    }
}

extern "C" void kernel_launch(void* const* d_in, const int* in_sizes, int n_in,
                              void* d_out, int out_size, void* d_ws, size_t ws_size,
                              hipStream_t stream) {
    const float* q = (const float*)d_in[0];
    const float* k = (const float*)d_in[1];
    const float* v = (const float*)d_in[2];
    float* out = (float*)d_out;

    // 4 identical idempotent launches: total = overhead + Tk_cold + 3*Tk_warm.
    // The dur_us delta vs R8 (single launch) measures Tk directly.
    lminf_kernel<<<NB, 512, 0, stream>>>(q, k, v, out);
    lminf_kernel<<<NB, 512, 0, stream>>>(q, k, v, out);
    lminf_kernel<<<NB, 512, 0, stream>>>(q, k, v, out);
    lminf_kernel<<<NB, 512, 0, stream>>>(q, k, v, out);
}

// Round 10
// 99.888 us; speedup vs baseline: 1.4548x; 1.4548x over previous
//
#include <hip/hip_runtime.h>

#define SEQ 8192
#define DIM 128
#define QR  8                          // query rows per wave
#define WPB 8                          // waves per block (512 threads)
#define RPB (QR * WPB)                 // 64 rows per block
#define NB  (2 * SEQ / RPB)            // 256 blocks = 1 per CU, single round
#define SROWS 120                      // staged K/V rows: [blkrow0-56, blkrow0+63]

// fp32 in / fp32 out. One wave handles QR=8 consecutive query rows [r0,r0+7];
// lane l owns key j = r0-56+l. Row rr's window is [r0-56, r0+rr] (57..64
// keys); dropped keys carry bias <= -57 -> relative weight < e^-46, invisible
// at fp32. Global sinks (j<100) only matter inside the window (rows i<157).
//
// R10 changes vs R8/R9 (measured: Tk_warm ~17us, Tk_cold ~37us):
//  * QR=8: per-row LDS-read + staging cost halves; NB=256 -> exactly 1
//    block/CU, ONE dispatch round (R8 had 2 sequential rounds), all cold
//    staging bursts in flight at once -> cold fetch BW-bound not latency.
//  * PV weights via v_readlane (VALU pipe, R6-proven) instead of 64 wsm
//    b128 LDS reads/wave; lsum via 6-step butterfly (48 ops) instead of 512
//    redundant adds; weights normalized before PV.
//  * LDS/wave ~0.9K cyc (was ~1.9K), single round -> LDS ~3us, VALU ~5us.
__global__ __launch_bounds__(512) void lminf_kernel(
    const float* __restrict__ qg,
    const float* __restrict__ kg,
    const float* __restrict__ vg,
    float* __restrict__ og)
{
    const int tid  = threadIdx.x;
    const int lane = tid & 63;
    const int wv   = __builtin_amdgcn_readfirstlane(tid >> 6);  // uniform 0..7

    // XCD-contiguity remap: XCD x owns contiguous work ids [32x, 32x+31]
    const int wk      = ((blockIdx.x & 7) << 5) | (blockIdx.x >> 3);
    const int blkrow0 = (wk * RPB) & (SEQ - 1);      // block's first row
    const int r0      = blkrow0 + wv * QR;           // wave's first row
    const long base   = (long)((wk * RPB) >> 13) * (SEQ * DIM);

    __shared__ float4 kds[SROWS * 32];               // 60 KB, chunk c at c^(row&7)
    __shared__ float4 vds[SROWS * 32];               // 60 KB, linear

    // ---- burst-stage K (XOR-swizzled) + V (linear), fully coalesced ----
    {
        const float4* kgp = (const float4*)(kg + base);
        const float4* vgp = (const float4*)(vg + base);
        #pragma unroll
        for (int it = 0; it < 8; ++it) {             // 7.5 avg iters of 512
            const int g = it * 512 + tid;
            if (g < SROWS * 32) {
                const int row = g >> 5;
                const int c   = g & 31;
                int gr = blkrow0 - 56 + row;
                if (gr < 0) gr = 0;                  // clamped rows get w=0
                kds[row * 32 + (c ^ (row & 7))] = kgp[gr * 32 + c];
                vds[row * 32 + c]               = vgp[gr * 32 + c];
            }
        }
    }
    __syncthreads();

    // ---- QK: K via swizzled ds_read_b128; q via wave-uniform loads ----
    const int j  = r0 - 56 + lane;              // lane's key
    const int lr = wv * QR + lane;              // staged local row of key j
    const int sw = lr & 7;
    const float4* krow = &kds[lr * 32];
    const float* qb = qg + base + (long)r0 * DIM;   // wave-uniform

    float acc[QR] = {0.f,0.f,0.f,0.f,0.f,0.f,0.f,0.f};
    #pragma unroll 8
    for (int c = 0; c < 32; ++c) {
        const float4 kk = krow[c ^ sw];
        #pragma unroll
        for (int rr = 0; rr < QR; ++rr) {
            const float4 qq = *(const float4*)(qb + rr * DIM + c * 4);
            acc[rr] += qq.x * kk.x + qq.y * kk.y + qq.z * kk.z + qq.w * kk.w;
        }
    }

    // ---- softmax: fixed stabilizer M=8 (s <= ~6); butterfly row-sum;
    //      normalize in-register -> PV needs no lsum, no wsm LDS ----
    float w[QR];
    #pragma unroll
    for (int rr = 0; rr < QR; ++rr) {
        float s = acc[rr] * 0.08838834764831845f + (float)(lane - 56 - rr);
        if (lane > 56 + rr || j < 0) s = -3.0e38f;  // causal + left edge
        const float e = __expf(s - 8.0f);           // masked -> exact 0
        float l = e;
        #pragma unroll
        for (int off = 32; off; off >>= 1) l += __shfl_xor(l, off);
        w[rr] = e * (1.0f / l);                     // l >= e^-14 > 0
    }

    // ---- PV: lane owns dims {2*lane, 2*lane+1}; V rows from LDS (b64);
    //      weights broadcast via v_readlane (SGPR index, uniform) ----
    float o0[QR] = {0.f,0.f,0.f,0.f,0.f,0.f,0.f,0.f};
    float o1[QR] = {0.f,0.f,0.f,0.f,0.f,0.f,0.f,0.f};
    #pragma unroll 16
    for (int k = 0; k < 64; ++k) {
        const float2 vp = *(const float2*)(
            (const float*)&vds[(wv * QR + k) * 32] + 2 * lane);
        #pragma unroll
        for (int rr = 0; rr < QR; ++rr) {
            const float wk_ = __uint_as_float(
                __builtin_amdgcn_readlane(__float_as_uint(w[rr]), k));
            o0[rr] += wk_ * vp.x;
            o1[rr] += wk_ * vp.y;
        }
    }

    // ---- store (coalesced float2 per lane per row) ----
    #pragma unroll
    for (int rr = 0; rr < QR; ++rr) {
        ((float2*)(og + base + (long)(r0 + rr) * DIM))[lane] =
            make_float2(o0[rr], o1[rr]);
    }
}

extern "C" void kernel_launch(void* const* d_in, const int* in_sizes, int n_in,
                              void* d_out, int out_size, void* d_ws, size_t ws_size,
                              hipStream_t stream) {
    const float* q = (const float*)d_in[0];
    const float* k = (const float*)d_in[1];
    const float* v = (const float*)d_in[2];
    float* out = (float*)d_out;

    lminf_kernel<<<NB, 512, 0, stream>>>(q, k, v, out);
}

// Round 11
// 91.954 us; speedup vs baseline: 1.5803x; 1.0863x over previous
//
#include <hip/hip_runtime.h>

#define SEQ 8192
#define DIM 128
#define QR  4                          // query rows per wave
#define WPB 8                          // waves per block (512 threads)
#define RPB (QR * WPB)                 // 32 rows per block
#define NB  (2 * SEQ / RPB)            // 512 blocks
#define SROWS 96                       // staged K/V rows: [blkrow0-64, blkrow0+31]

// R11 = R8 main kernel VERBATIM (warm time directly measured at 17.1us in R9)
// + an XCD-matched prefetch kernel that absorbs the cold-miss cost at
// streaming BW (the harness's own fills prove cold HBM streams at 6.1 TB/s).
// Prefetch block b -> XCD b%8; XCD x's main blocks own global rows
// [2048x, 2048x+2048) under the (blk&7)<<6 swizzle; per-XCD footprint
// 3x1.05MB = 3.1MB < 4MB L2.

__global__ __launch_bounds__(256) void prefetch_kernel(
    const float* __restrict__ qg,
    const float* __restrict__ kg,
    const float* __restrict__ vg,
    float* __restrict__ ws)
{
    const int xcd = blockIdx.x & 7;
    const int w   = blockIdx.x >> 3;                 // 0..255
    // global rows [2048*xcd + 8*w, +8): 8 rows x 128 dims = 256 float4/tensor
    const long f4base = ((long)xcd * 2048 + (long)w * 8) * (DIM / 4);
    const long idx = f4base + threadIdx.x;
    const float4 a = ((const float4*)qg)[idx];
    const float4 b = ((const float4*)kg)[idx];
    const float4 c = ((const float4*)vg)[idx];
    const float s = a.x + a.y + a.z + a.w + b.x + b.y + b.z + b.w
                  + c.x + c.y + c.z + c.w;
    if (s == 1.2345678e38f) ws[0] = s;   // never true; keeps loads live
}

__global__ __launch_bounds__(512) void lminf_kernel(
    const float* __restrict__ qg,
    const float* __restrict__ kg,
    const float* __restrict__ vg,
    float* __restrict__ og)
{
    const int tid  = threadIdx.x;
    const int lane = tid & 63;
    const int wv   = __builtin_amdgcn_readfirstlane(tid >> 6);  // uniform 0..7

    const int wk      = ((blockIdx.x & 7) << 6) + (blockIdx.x >> 3);
    const int rowblk  = wk * RPB + wv * QR;          // wave's first query row
    const int r0      = rowblk & (SEQ - 1);
    const int blkrow0 = (wk * RPB) & (SEQ - 1);      // block's first row
    const long base   = (long)((wk * RPB) >> 13) * (SEQ * DIM);

    __shared__ float4 kds[SROWS * 32];               // 48 KB, chunk c at c^(row&7)
    __shared__ float4 vds[SROWS * 32];               // 48 KB, linear
    __shared__ float4 wsm[WPB][64];                  // 8 KB, per-key packed e

    // ---- burst-stage K (XOR-swizzled) and V (linear), fully coalesced ----
    {
        const float4* kgp = (const float4*)(kg + base);
        const float4* vgp = (const float4*)(vg + base);
        #pragma unroll
        for (int it = 0; it < (SROWS * 32) / 512; ++it) {   // 6 iters
            const int g   = it * 512 + tid;
            const int row = g >> 5;
            const int c   = g & 31;
            int gr = blkrow0 - 64 + row;
            if (gr < 0) gr = 0;                 // clamped rows get weight 0
            kds[row * 32 + (c ^ (row & 7))] = kgp[gr * 32 + c];
            vds[row * 32 + c]               = vgp[gr * 32 + c];
        }
    }
    __syncthreads();

    // ---- QK: K via swizzled ds_read_b128; q via wave-uniform s_load ----
    const int w0 = r0 - 60;                     // key owned by lane 0
    const int j  = w0 + lane;
    const int lr = lane + wv * QR + 4;          // staged local row of key j
    const int sw = lr & 7;
    const float4* krow = &kds[lr * 32];
    const float* qb = qg + base + (long)r0 * DIM;   // wave-uniform

    float acc[QR] = {0.f, 0.f, 0.f, 0.f};
    #pragma unroll 8
    for (int c = 0; c < 32; ++c) {
        const float4 kk = krow[c ^ sw];
        #pragma unroll
        for (int rr = 0; rr < QR; ++rr) {
            const float4 qq = *(const float4*)(qb + rr * DIM + c * 4);
            acc[rr] += qq.x * kk.x + qq.y * kk.y + qq.z * kk.z + qq.w * kk.w;
        }
    }

    // ---- shuffle-free softmax numerator: fixed stabilizer M = 8 ----
    float e[QR];
    #pragma unroll
    for (int rr = 0; rr < QR; ++rr) {
        const int i = r0 + rr;
        float s = acc[rr] * 0.08838834764831845f + (float)(j - i);  // bias
        if (j > i || j < 0) s = -3.0e38f;       // causal + left-edge mask
        e[rr] = __expf(s - 8.0f);               // masked lanes -> exact 0
    }
    wsm[wv][lane] = make_float4(e[0], e[1], e[2], e[3]);

    // ---- PV: pure LDS; weights uniform broadcast; l folded into loop ----
    float o0[QR] = {0.f, 0.f, 0.f, 0.f};
    float o1[QR] = {0.f, 0.f, 0.f, 0.f};
    float lsum[QR] = {0.f, 0.f, 0.f, 0.f};
    #pragma unroll 16
    for (int k = 0; k < 64; ++k) {
        const float2 vpair = *(const float2*)(
            (const float*)&vds[(k + wv * QR + 4) * 32] + 2 * lane);
        const float4 wk4 = wsm[wv][k];          // uniform addr -> broadcast
        lsum[0] += wk4.x;  lsum[1] += wk4.y;
        lsum[2] += wk4.z;  lsum[3] += wk4.w;
        o0[0] += wk4.x * vpair.x;  o1[0] += wk4.x * vpair.y;
        o0[1] += wk4.y * vpair.x;  o1[1] += wk4.y * vpair.y;
        o0[2] += wk4.z * vpair.x;  o1[2] += wk4.z * vpair.y;
        o0[3] += wk4.w * vpair.x;  o1[3] += wk4.w * vpair.y;
    }

    // ---- normalize and store (coalesced float2 per lane per row) ----
    #pragma unroll
    for (int rr = 0; rr < QR; ++rr) {
        const float rl = 1.0f / lsum[rr];       // l >= e^-14 > 0 always
        ((float2*)(og + base + (long)(r0 + rr) * DIM))[lane] =
            make_float2(o0[rr] * rl, o1[rr] * rl);
    }
}

extern "C" void kernel_launch(void* const* d_in, const int* in_sizes, int n_in,
                              void* d_out, int out_size, void* d_ws, size_t ws_size,
                              hipStream_t stream) {
    const float* q = (const float*)d_in[0];
    const float* k = (const float*)d_in[1];
    const float* v = (const float*)d_in[2];
    float* out = (float*)d_out;

    // 1) stream q/k/v into the right XCDs' L2 at full BW (cold-miss absorber)
    prefetch_kernel<<<2048, 256, 0, stream>>>(q, k, v, (float*)d_ws);
    // 2) R8 kernel, now L2-warm (R9-measured warm time: 17.1 us)
    lminf_kernel<<<NB, 512, 0, stream>>>(q, k, v, out);
}